// Round 7
// baseline (98.163 us; speedup 1.0000x reference)
//
#include <hip/hip_runtime.h>

#define NF 7
#define NR 128
#define ROWS 64     // rows per block (main kernel)
#define CITERS 8    // phase-C iterations (8 rows each)

typedef float v4f __attribute__((ext_vector_type(4)));

// ws float layout:
//   [0..31]   : 128 rule masks packed 4/word (as uint)
//   [32],[33] : alpha, w
//   [40+8j..] : per-MF params j=0..13: mu, i2s2, q0, q1, q2, q3, invL, invR

__global__ __launch_bounds__(128) void anfis_prep(
    const float* __restrict__ mu_g,  const float* __restrict__ sig_g,
    const float* __restrict__ ta, const float* __restrict__ tb,
    const float* __restrict__ tc, const float* __restrict__ td,
    const float* __restrict__ mf_mix, const float* __restrict__ tnw,
    const int*   __restrict__ rule_idx,
    float* __restrict__ ws)
{
    __shared__ unsigned char s_m[NR];
    const int tid = threadIdx.x;

    if (tid < NR) {
        int m = 0;
        #pragma unroll
        for (int i = 0; i < NF; ++i)
            if (rule_idx[tid * NF + i] != 0) m |= (1 << i);
        s_m[tid] = (unsigned char)m;
    }
    __syncthreads();
    if (tid < 32)
        ((unsigned int*)ws)[tid] = ((const unsigned int*)s_m)[tid];

    if (tid == 32) {
        ws[32] = 1.0f / (1.0f + __expf(-mf_mix[0]));
        ws[33] = 1.0f / (1.0f + __expf(-tnw[0]));
    }

    if (tid < 14) {
        const float mu_j = mu_g[tid];
        float sg = fmaxf(sig_g[tid], 1e-6f);
        const float i2s2 = 1.0f / (2.0f * sg * sg);

        float p0 = ta[tid], p1 = tb[tid], p2 = tc[tid], p3 = td[tid];
        float lo, hi;
        lo = fminf(p0, p1); hi = fmaxf(p0, p1); p0 = lo; p1 = hi;
        lo = fminf(p2, p3); hi = fmaxf(p2, p3); p2 = lo; p3 = hi;
        lo = fminf(p0, p2); hi = fmaxf(p0, p2); p0 = lo; p2 = hi;
        lo = fminf(p1, p3); hi = fmaxf(p1, p3); p1 = lo; p3 = hi;
        lo = fminf(p1, p2); hi = fmaxf(p1, p2); p1 = lo; p2 = hi;

        float* dst = ws + 40 + 8 * tid;
        dst[0] = mu_j;
        dst[1] = i2s2;
        dst[2] = p0;
        dst[3] = p1;
        dst[4] = p2;
        dst[5] = p3;
        dst[6] = 1.0f / (p1 - p0 + 1e-6f);
        dst[7] = 1.0f / (p3 - p2 + 1e-6f);
    }
}

__global__ __launch_bounds__(256) void anfis_main(
    const float* __restrict__ x,
    const float* __restrict__ consequent,   // [128][8]
    const float* __restrict__ ws,
    float* __restrict__ out,                // [B]
    float* __restrict__ nf_out,             // [B][128]
    float* __restrict__ mem_out,            // [B][14]
    int nrows)
{
    __shared__ float s_x[ROWS][8];          // [1, x0..x6]
    __shared__ float s_mem[ROWS][16];       // 14 used

    const int tid  = threadIdx.x;
    const int base = blockIdx.x * ROWS;

    const float alpha = ws[32];
    const float w     = ws[33];
    const float a1 = 1.0f - alpha, w1 = 1.0f - w;

    // ---- phase B: all 64 rows' memberships upfront (4 rows/thread) ----
    {
        const int j   = tid & 15;
        const int r16 = tid >> 4;

        float mu_j = 0.f, i2s2 = 0.f, q0 = 0.f, q1 = 0.f, q2 = 0.f, q3 = 0.f;
        float invL = 0.f, invR = 0.f;
        if (j < 14) {
            const float4 Pa = ((const float4*)(ws + 40))[2 * j];
            const float4 Pb = ((const float4*)(ws + 40))[2 * j + 1];
            mu_j = Pa.x; i2s2 = Pa.y; q0 = Pa.z; q1 = Pa.w;
            q2 = Pb.x; q3 = Pb.y; invL = Pb.z; invR = Pb.w;
        }

        #pragma unroll
        for (int h = 0; h < 4; ++h) {
            const int rl  = r16 + 16 * h;
            const int row = base + rl;
            const bool live = (row < nrows);
            if (j < 14) {
                const float xi = live ? x[row * NF + (j >> 1)] : 0.0f;
                const float dm = xi - mu_j;
                const float gauss = __expf(-(dm * dm) * i2s2);
                float left = (xi - q0) * invL;
                left = fminf(fmaxf(left, 0.f), 1.f);
                const float flat = (xi >= q1 && xi <= q2) ? 1.f : 0.f;
                float right = (q3 - xi) * invR;
                right = fminf(fmaxf(right, 0.f), 1.f);
                const float trap = fmaxf(fminf(left, right), flat);
                const float m = fmaf(alpha, gauss, a1 * trap);
                s_mem[rl][j] = m;
                if (live) __builtin_nontemporal_store(m, &mem_out[row * 14 + j]);
                if ((j & 1) == 0) s_x[rl][1 + (j >> 1)] = xi;
            } else if (j == 15) {
                s_x[rl][0] = 1.0f;
            }
        }
    }
    __syncthreads();   // the only barrier

    // ---- phase C: 8 row iterations, 4 rules/lane ----
    const int g  = tid >> 5;        // row-group 0..7
    const int jj = tid & 31;        // lane in group
    const unsigned int msks = ((const unsigned int*)ws)[jj];
    const int r0 = 4 * jj;
    const float4* __restrict__ cq = (const float4*)consequent;

    // hoist this lane's 4 consequent rows (32 B each) once
    float4 c[8];
    #pragma unroll
    for (int k = 0; k < 8; ++k) c[k] = cq[2 * r0 + k];

    // prefix selectors (features 0..4 constant across this lane's 4 rules)
    const unsigned int m0 = msks & 0xffu;

    #pragma unroll 2
    for (int it = 0; it < CITERS; ++it) {
        const int rl  = g + 8 * it;
        const int row = base + rl;
        const bool live = (row < nrows);

        const float4 xa0 = *(const float4*)&s_x[rl][0];
        const float4 xa1 = *(const float4*)&s_x[rl][4];
        const float4 mA = *(const float4*)&s_mem[rl][0];
        const float4 mB = *(const float4*)&s_mem[rl][4];
        const float4 mC = *(const float4*)&s_mem[rl][8];
        const float2 mD = *(const float2*)&s_mem[rl][12];

        const float p0 = (m0 & 1u)  ? mA.y : mA.x;
        const float p1 = (m0 & 2u)  ? mA.w : mA.z;
        const float p2 = (m0 & 4u)  ? mB.y : mB.x;
        const float p3 = (m0 & 8u)  ? mB.w : mB.z;
        const float p4 = (m0 & 16u) ? mC.y : mC.x;
        const float P5 = ((p0 * p1) * (p2 * p3)) * p4;
        const float M5 = fminf(fminf(fminf(p0, p1), fminf(p2, p3)), p4);

        float f[4];
        float S = 0.f, dot = 0.f;
        #pragma unroll
        for (int k = 0; k < 4; ++k) {
            const unsigned int mk = msks >> (8 * k);
            const float g5 = (mk & 0x20u) ? mC.w : mC.z;
            const float g6 = (mk & 0x40u) ? mD.y : mD.x;
            const float prod = P5 * (g5 * g6);
            const float mn   = fminf(M5, fminf(g5, g6));
            const float fr   = fmaf(w, prod, w1 * mn);

            const float4 c0 = c[2 * k];
            const float4 c1 = c[2 * k + 1];
            float ro = c0.x * xa0.x;
            ro = fmaf(c0.y, xa0.y, ro);
            ro = fmaf(c0.z, xa0.z, ro);
            ro = fmaf(c0.w, xa0.w, ro);
            ro = fmaf(c1.x, xa1.x, ro);
            ro = fmaf(c1.y, xa1.y, ro);
            ro = fmaf(c1.z, xa1.z, ro);
            ro = fmaf(c1.w, xa1.w, ro);

            f[k] = fr;
            S += fr;
            dot = fmaf(fr, ro, dot);
        }

        #pragma unroll
        for (int off = 1; off < 32; off <<= 1) {
            S   += __shfl_xor(S, off, 64);
            dot += __shfl_xor(dot, off, 64);
        }
        const float invS = 1.0f / (S + 1e-8f);

        if (live) {
            v4f nf4;
            nf4.x = f[0] * invS;
            nf4.y = f[1] * invS;
            nf4.z = f[2] * invS;
            nf4.w = f[3] * invS;
            __builtin_nontemporal_store(nf4, (v4f*)&nf_out[(size_t)row * NR + r0]);
            if (jj == 0) out[row] = dot * invS;
        }
    }
}

extern "C" void kernel_launch(void* const* d_in, const int* in_sizes, int n_in,
                              void* d_out, int out_size, void* d_ws, size_t ws_size,
                              hipStream_t stream) {
    const float* x     = (const float*)d_in[0];
    const float* mu_g  = (const float*)d_in[1];
    const float* sig_g = (const float*)d_in[2];
    const float* ta    = (const float*)d_in[3];
    const float* tb    = (const float*)d_in[4];
    const float* tc    = (const float*)d_in[5];
    const float* td    = (const float*)d_in[6];
    const float* mfm   = (const float*)d_in[7];
    const float* tnw   = (const float*)d_in[8];
    const float* cons  = (const float*)d_in[9];
    const int*   ridx  = (const int*)d_in[10];

    const int nrows = in_sizes[0] / NF;            // 65536

    float* out     = (float*)d_out;
    float* nf_out  = out + nrows;
    float* mem_out = nf_out + (size_t)nrows * NR;
    float* ws      = (float*)d_ws;

    anfis_prep<<<1, 128, 0, stream>>>(mu_g, sig_g, ta, tb, tc, td,
                                      mfm, tnw, ridx, ws);

    const int grid = (nrows + ROWS - 1) / ROWS;
    anfis_main<<<grid, 256, 0, stream>>>(x, cons, ws,
                                         out, nf_out, mem_out, nrows);
}

// Round 8
// 95.174 us; speedup vs baseline: 1.0314x; 1.0314x over previous
//
#include <hip/hip_runtime.h>

#define NF 7
#define NR 128
#define ROWS 64     // rows per block
#define CITERS 8    // phase-C iterations (8 rows each)

typedef float v4f __attribute__((ext_vector_type(4)));

__global__ __launch_bounds__(256) void anfis_kernel(
    const float* __restrict__ x,
    const float* __restrict__ mu_g,  const float* __restrict__ sig_g,
    const float* __restrict__ ta, const float* __restrict__ tb,
    const float* __restrict__ tc, const float* __restrict__ td,
    const float* __restrict__ mf_mix, const float* __restrict__ tnw,
    const float* __restrict__ consequent,   // [128][8]
    const int*   __restrict__ rule_idx,     // [128][7]
    float* __restrict__ out,                // [B]
    float* __restrict__ nf_out,             // [B][128]
    float* __restrict__ mem_out,            // [B][14]
    int nrows)
{
    __shared__ float s_x[ROWS][8];          // [1, x0..x6]
    __shared__ float s_mem[ROWS][16];       // 14 used
    __shared__ unsigned int s_mask32[32];   // 128 rule masks packed 4/word

    const int tid  = threadIdx.x;
    const int base = blockIdx.x * ROWS;

    // ---- phase A: rule masks (once per block) ----
    if (tid < NR) {
        int m = 0;
        #pragma unroll
        for (int i = 0; i < NF; ++i)
            if (rule_idx[tid * NF + i] != 0) m |= (1 << i);
        ((unsigned char*)s_mask32)[tid] = (unsigned char)m;
    }

    const float alpha = 1.0f / (1.0f + __expf(-mf_mix[0]));
    const float w     = 1.0f / (1.0f + __expf(-tnw[0]));
    const float a1 = 1.0f - alpha, w1 = 1.0f - w;

    // ---- phase B: all 64 rows' memberships upfront (4 rows/thread) ----
    {
        const int j   = tid & 15;
        const int r16 = tid >> 4;

        float mu_j = 0.f, i2s2 = 0.f, q0 = 0.f, q1 = 0.f, q2 = 0.f, q3 = 0.f;
        float invL = 0.f, invR = 0.f;
        if (j < 14) {
            mu_j = mu_g[j];
            float sg = fmaxf(sig_g[j], 1e-6f);
            i2s2 = 1.0f / (2.0f * sg * sg);
            float p0 = ta[j], p1 = tb[j], p2 = tc[j], p3 = td[j];
            float lo, hi;
            lo = fminf(p0, p1); hi = fmaxf(p0, p1); p0 = lo; p1 = hi;
            lo = fminf(p2, p3); hi = fmaxf(p2, p3); p2 = lo; p3 = hi;
            lo = fminf(p0, p2); hi = fmaxf(p0, p2); p0 = lo; p2 = hi;
            lo = fminf(p1, p3); hi = fmaxf(p1, p3); p1 = lo; p3 = hi;
            lo = fminf(p1, p2); hi = fmaxf(p1, p2); p1 = lo; p2 = hi;
            q0 = p0; q1 = p1; q2 = p2; q3 = p3;
            invL = 1.0f / (p1 - p0 + 1e-6f);
            invR = 1.0f / (p3 - p2 + 1e-6f);
        }

        #pragma unroll
        for (int h = 0; h < 4; ++h) {
            const int rl  = r16 + 16 * h;
            const int row = base + rl;
            const bool live = (row < nrows);
            if (j < 14) {
                const float xi = live ? x[row * NF + (j >> 1)] : 0.0f;
                const float dm = xi - mu_j;
                const float gauss = __expf(-(dm * dm) * i2s2);
                float left = (xi - q0) * invL;
                left = fminf(fmaxf(left, 0.f), 1.f);
                const float flat = (xi >= q1 && xi <= q2) ? 1.f : 0.f;
                float right = (q3 - xi) * invR;
                right = fminf(fmaxf(right, 0.f), 1.f);
                const float trap = fmaxf(fminf(left, right), flat);
                const float m = fmaf(alpha, gauss, a1 * trap);
                s_mem[rl][j] = m;
                if (live) __builtin_nontemporal_store(m, &mem_out[row * 14 + j]);
                if ((j & 1) == 0) s_x[rl][1 + (j >> 1)] = xi;
            } else if (j == 15) {
                s_x[rl][0] = 1.0f;
            }
        }
    }
    __syncthreads();   // the only barrier

    // ---- phase C: 8 row iterations, 4 rules/lane ----
    const int g  = tid >> 5;        // row-group 0..7
    const int jj = tid & 31;        // lane in group
    const unsigned int msks = s_mask32[jj];
    const int r0 = 4 * jj;
    const float4* __restrict__ cq = (const float4*)consequent;

    // hoist this lane's 4 consequent rows (32 B each) once
    float4 c[8];
    #pragma unroll
    for (int k = 0; k < 8; ++k) c[k] = cq[2 * r0 + k];

    // prefix selectors (features 0..4 constant across this lane's 4 rules)
    const unsigned int m0 = msks & 0xffu;

    #pragma unroll 2
    for (int it = 0; it < CITERS; ++it) {
        const int rl  = g + 8 * it;
        const int row = base + rl;
        const bool live = (row < nrows);

        const float4 xa0 = *(const float4*)&s_x[rl][0];
        const float4 xa1 = *(const float4*)&s_x[rl][4];
        const float4 mA = *(const float4*)&s_mem[rl][0];
        const float4 mB = *(const float4*)&s_mem[rl][4];
        const float4 mC = *(const float4*)&s_mem[rl][8];
        const float2 mD = *(const float2*)&s_mem[rl][12];

        const float p0 = (m0 & 1u)  ? mA.y : mA.x;
        const float p1 = (m0 & 2u)  ? mA.w : mA.z;
        const float p2 = (m0 & 4u)  ? mB.y : mB.x;
        const float p3 = (m0 & 8u)  ? mB.w : mB.z;
        const float p4 = (m0 & 16u) ? mC.y : mC.x;
        const float P5 = ((p0 * p1) * (p2 * p3)) * p4;
        const float M5 = fminf(fminf(fminf(p0, p1), fminf(p2, p3)), p4);

        float f[4];
        float S = 0.f, dot = 0.f;
        #pragma unroll
        for (int k = 0; k < 4; ++k) {
            const unsigned int mk = msks >> (8 * k);
            const float g5 = (mk & 0x20u) ? mC.w : mC.z;
            const float g6 = (mk & 0x40u) ? mD.y : mD.x;
            const float prod = P5 * (g5 * g6);
            const float mn   = fminf(M5, fminf(g5, g6));
            const float fr   = fmaf(w, prod, w1 * mn);

            const float4 c0 = c[2 * k];
            const float4 c1 = c[2 * k + 1];
            float ro = c0.x * xa0.x;
            ro = fmaf(c0.y, xa0.y, ro);
            ro = fmaf(c0.z, xa0.z, ro);
            ro = fmaf(c0.w, xa0.w, ro);
            ro = fmaf(c1.x, xa1.x, ro);
            ro = fmaf(c1.y, xa1.y, ro);
            ro = fmaf(c1.z, xa1.z, ro);
            ro = fmaf(c1.w, xa1.w, ro);

            f[k] = fr;
            S += fr;
            dot = fmaf(fr, ro, dot);
        }

        #pragma unroll
        for (int off = 1; off < 32; off <<= 1) {
            S   += __shfl_xor(S, off, 64);
            dot += __shfl_xor(dot, off, 64);
        }
        const float invS = 1.0f / (S + 1e-8f);

        if (live) {
            v4f nf4;
            nf4.x = f[0] * invS;
            nf4.y = f[1] * invS;
            nf4.z = f[2] * invS;
            nf4.w = f[3] * invS;
            __builtin_nontemporal_store(nf4, (v4f*)&nf_out[(size_t)row * NR + r0]);
            if (jj == 0) __builtin_nontemporal_store(dot * invS, &out[row]);
        }
    }
}

extern "C" void kernel_launch(void* const* d_in, const int* in_sizes, int n_in,
                              void* d_out, int out_size, void* d_ws, size_t ws_size,
                              hipStream_t stream) {
    const float* x     = (const float*)d_in[0];
    const float* mu_g  = (const float*)d_in[1];
    const float* sig_g = (const float*)d_in[2];
    const float* ta    = (const float*)d_in[3];
    const float* tb    = (const float*)d_in[4];
    const float* tc    = (const float*)d_in[5];
    const float* td    = (const float*)d_in[6];
    const float* mfm   = (const float*)d_in[7];
    const float* tnw   = (const float*)d_in[8];
    const float* cons  = (const float*)d_in[9];
    const int*   ridx  = (const int*)d_in[10];

    const int nrows = in_sizes[0] / NF;            // 65536

    float* out     = (float*)d_out;
    float* nf_out  = out + nrows;
    float* mem_out = nf_out + (size_t)nrows * NR;

    const int grid = (nrows + ROWS - 1) / ROWS;
    anfis_kernel<<<grid, 256, 0, stream>>>(x, mu_g, sig_g, ta, tb, tc, td,
                                           mfm, tnw, cons, ridx,
                                           out, nf_out, mem_out, nrows);
}